// Round 1
// baseline (1664.068 us; speedup 1.0000x reference)
//
#include <hip/hip_runtime.h>
#include <stdint.h>

// GRANMixtureBernoulli: E=4194304 edges, K=20 comps, S=4096 segments.
// loss = -mean_over_E( logsumexp_k( -radj[s,k] + logsoftmax_k(ralpha[s,k]/cnt[s]) ) summed over s ) ... see ref.
// Pipeline: memset(tables) -> pack+count -> role-split segment accumulate (LDS partial, atomic flush) -> finalize.

#define S_SEG 4096
#define K_COMP 20

__device__ __forceinline__ float sp_f(float x) {
    // softplus(x) = max(x,0) + log1p(exp(-|x|)); fast-math forms are fine for 1.5e-2 scalar tolerance
    return fmaxf(x, 0.f) + __logf(1.f + __expf(-fabsf(x)));
}

__device__ __forceinline__ void gatomic_add_f(float* p, float v) {
    __hip_atomic_fetch_add(p, v, __ATOMIC_RELAXED, __HIP_MEMORY_SCOPE_AGENT);
}

// ---------------- pre-kernel: pack idx+label into u16, histogram counts ----------------
__global__ __launch_bounds__(256) void pack_count_kernel(
    const int* __restrict__ sidx, const float* __restrict__ label,
    unsigned short* __restrict__ packed, unsigned int* __restrict__ g_cnt,
    int E4, int doPack)
{
    __shared__ unsigned int hist[S_SEG];
    for (int i = threadIdx.x; i < S_SEG; i += 256) hist[i] = 0u;
    __syncthreads();

    const int4*   s4 = (const int4*)sidx;
    const float4* l4 = (const float4*)label;
    int gt = blockIdx.x * 256 + threadIdx.x;
    int stride = gridDim.x * 256;
    for (int i = gt; i < E4; i += stride) {
        int4   sv = s4[i];
        float4 lv = l4[i];
        atomicAdd(&hist[sv.x & 4095], 1u);
        atomicAdd(&hist[sv.y & 4095], 1u);
        atomicAdd(&hist[sv.z & 4095], 1u);
        atomicAdd(&hist[sv.w & 4095], 1u);
        if (doPack) {
            ushort4 pk;
            pk.x = (unsigned short)((sv.x & 4095) | (lv.x != 0.f ? 0x8000 : 0));
            pk.y = (unsigned short)((sv.y & 4095) | (lv.y != 0.f ? 0x8000 : 0));
            pk.z = (unsigned short)((sv.z & 4095) | (lv.z != 0.f ? 0x8000 : 0));
            pk.w = (unsigned short)((sv.w & 4095) | (lv.w != 0.f ? 0x8000 : 0));
            ((ushort4*)packed)[i] = pk;
        }
    }
    __syncthreads();
    for (int i = threadIdx.x; i < S_SEG; i += 256) {
        unsigned int c = hist[i];
        if (c) atomicAdd(&g_cnt[i], c);
    }
}

// ---------------- accumulation kernel: grid.x = 10 roles (5 adj chunks, 5 alpha chunks) ----------------
template<bool PACKED>
__global__ __launch_bounds__(256) void seg_accum_kernel(
    const float* __restrict__ theta, const float* __restrict__ alpha,
    const unsigned short* __restrict__ packed,
    const int* __restrict__ sidx, const float* __restrict__ label,
    float* __restrict__ g_adj, float* __restrict__ g_alp,
    int ntiles)
{
    // LDS partial table, column-major [kk][s] so bank = s % 32 (random s -> ~2-way, free)
    __shared__ float tab[4 * S_SEG];
    for (int i = threadIdx.x; i < 4 * S_SEG; i += 256) tab[i] = 0.f;
    __syncthreads();

    const int  role  = blockIdx.x;          // 0..9
    const bool isAdj = role < 5;
    const int  c4    = isAdj ? role : role - 5;   // which float4 of the 5 per 20-float row
    const float4* src4 = (const float4*)(isAdj ? theta : alpha);
    const int nY = gridDim.y;

    for (int t = blockIdx.y; t < ntiles; t += 2 * nY) {
        const int tB = t + nY;
        const bool hasB = (tB < ntiles);

        int eA = t * 256 + threadIdx.x;
        float4 vA = src4[(size_t)eA * 5 + c4];
        int sA; float labA;
        if (PACKED) {
            unsigned short p = packed[eA];
            sA = p & 4095; labA = (p & 0x8000) ? 1.f : 0.f;
        } else {
            sA = sidx[eA] & 4095; labA = label[eA];
        }

        int eB = 0; float4 vB; int sB = 0; float labB = 0.f;
        if (hasB) {
            eB = tB * 256 + threadIdx.x;
            vB = src4[(size_t)eB * 5 + c4];
            if (PACKED) {
                unsigned short p = packed[eB];
                sB = p & 4095; labB = (p & 0x8000) ? 1.f : 0.f;
            } else {
                sB = sidx[eB] & 4095; labB = label[eB];
            }
        }

        if (isAdj) {
            vA.x = sp_f(vA.x) - vA.x * labA;
            vA.y = sp_f(vA.y) - vA.y * labA;
            vA.z = sp_f(vA.z) - vA.z * labA;
            vA.w = sp_f(vA.w) - vA.w * labA;
        }
        atomicAdd(&tab[            sA], vA.x);
        atomicAdd(&tab[1 * S_SEG + sA], vA.y);
        atomicAdd(&tab[2 * S_SEG + sA], vA.z);
        atomicAdd(&tab[3 * S_SEG + sA], vA.w);

        if (hasB) {
            if (isAdj) {
                vB.x = sp_f(vB.x) - vB.x * labB;
                vB.y = sp_f(vB.y) - vB.y * labB;
                vB.z = sp_f(vB.z) - vB.z * labB;
                vB.w = sp_f(vB.w) - vB.w * labB;
            }
            atomicAdd(&tab[            sB], vB.x);
            atomicAdd(&tab[1 * S_SEG + sB], vB.y);
            atomicAdd(&tab[2 * S_SEG + sB], vB.z);
            atomicAdd(&tab[3 * S_SEG + sB], vB.w);
        }
    }
    __syncthreads();

    // flush LDS partial to global table with fp32 atomics (~16K per block)
    float* g = isAdj ? g_adj : g_alp;
    const int k0 = c4 * 4;
    for (int j = threadIdx.x; j < 4 * S_SEG; j += 256) {
        int kk = j >> 12;
        int s  = j & 4095;
        gatomic_add_f(&g[s * K_COMP + k0 + kk], tab[j]);
    }
}

// ---------------- finalize: one block ----------------
__global__ __launch_bounds__(256) void finalize_kernel(
    const float* __restrict__ g_adj, const float* __restrict__ g_alp,
    const unsigned int* __restrict__ g_cnt, float* __restrict__ out, float Ef)
{
    float local = 0.f;
    for (int s = threadIdx.x; s < S_SEG; s += 256) {
        float c = (float)g_cnt[s];
        if (c < 1.f) c = 1.f;
        float inv = 1.f / c;

        float a[K_COMP];
        float am = -1e30f;
        #pragma unroll
        for (int k = 0; k < K_COMP; ++k) {
            a[k] = g_alp[s * K_COMP + k] * inv;
            am = fmaxf(am, a[k]);
        }
        float den = 0.f;
        #pragma unroll
        for (int k = 0; k < K_COMP; ++k) den += __expf(a[k] - am);
        float lse = am + __logf(den);

        float t[K_COMP];
        float tm = -1e30f;
        #pragma unroll
        for (int k = 0; k < K_COMP; ++k) {
            t[k] = (a[k] - lse) - g_adj[s * K_COMP + k];
            tm = fmaxf(tm, t[k]);
        }
        float d2 = 0.f;
        #pragma unroll
        for (int k = 0; k < K_COMP; ++k) d2 += __expf(t[k] - tm);
        local += tm + __logf(d2);
    }

    __shared__ float red[256];
    red[threadIdx.x] = local;
    __syncthreads();
    for (int o = 128; o > 0; o >>= 1) {
        if (threadIdx.x < o) red[threadIdx.x] += red[threadIdx.x + o];
        __syncthreads();
    }
    if (threadIdx.x == 0) out[0] = -red[0] / Ef;
}

extern "C" void kernel_launch(void* const* d_in, const int* in_sizes, int n_in,
                              void* d_out, int out_size, void* d_ws, size_t ws_size,
                              hipStream_t stream)
{
    const float* label = (const float*)d_in[0];
    const float* theta = (const float*)d_in[1];
    const float* alpha = (const float*)d_in[2];
    const int*   sidx  = (const int*)d_in[3];
    const int E = in_sizes[0];

    // ws layout: [radj 4096*20 f32][ralpha 4096*20 f32][count 4096 u32][packed E u16]
    float* g_adj = (float*)d_ws;
    float* g_alp = g_adj + S_SEG * K_COMP;
    unsigned int* g_cnt = (unsigned int*)(g_alp + S_SEG * K_COMP);
    const size_t tablesBytes = (size_t)S_SEG * K_COMP * 4 * 2 + (size_t)S_SEG * 4; // 671744
    unsigned short* packed = (unsigned short*)((char*)d_ws + tablesBytes);
    const int doPack = (ws_size >= tablesBytes + (size_t)E * 2) ? 1 : 0;

    hipMemsetAsync(d_ws, 0, tablesBytes, stream);

    pack_count_kernel<<<256, 256, 0, stream>>>(sidx, label, packed, g_cnt, E / 4, doPack);

    const int ntiles = E / 256;
    dim3 grid(10, 48);
    if (doPack)
        seg_accum_kernel<true><<<grid, 256, 0, stream>>>(theta, alpha, packed, sidx, label,
                                                         g_adj, g_alp, ntiles);
    else
        seg_accum_kernel<false><<<grid, 256, 0, stream>>>(theta, alpha, packed, sidx, label,
                                                          g_adj, g_alp, ntiles);

    finalize_kernel<<<1, 256, 0, stream>>>(g_adj, g_alp, g_cnt, (float*)d_out, (float)E);
}